// Round 8
// baseline (92.780 us; speedup 1.0000x reference)
//
#include <hip/hip_runtime.h>

#define DEVFN __device__ __forceinline__

constexpr int BNN = 64 * 64 * 64;              // 262144 per output tensor
constexpr float SCALE = 0.08838834764831845f;  // 1/sqrt(128)
constexpr float NSLOPE = 0.01f;

// ---- ws layout (floats) ---- (11.93 MB, proven)
constexpr int OFF_WPRET = 0;       // [64][128]
constexpr int OFF_WQT   = 8192;    // [128][128] (make_M input)
constexpr int OFF_M     = 24576;   // [128][128]  M = Wq^T Wk
constexpr int OFF_WSET  = 40960;   // [128][128]
constexpr int OFF_WSAPT = 57344;   // [96][128]
constexpr int OFF_WAVT  = 69632;   // [128][128]
constexpr int OFF_WF1T  = 86016;   // [128][64]
constexpr int OFF_E     = 98304;    // [4096][128] e row-major
constexpr int OFF_Q     = 622592;   // [4096][128] f then f2 (same-row aliasing, safe)
constexpr int OFF_ET    = 1146880;  // [B][128][64] e feature-major
constexpr int OFF_SET   = 1671168;  // [B][128][64] se feature-major
constexpr int OFF_AVACT = 2195456;  // [B][64][128]
constexpr int OFF_HD    = 2719744;  // [B][64][64]

// ============ staging: global (tight) -> LDS (padded pitch), 512 threads ============

DEVFN void st128(int tid, const float* __restrict__ src, float* __restrict__ Bs, int rows) {
  const int n4 = rows * 32;
  for (int idx = tid; idx < n4; idx += 512) {
    const int r = idx >> 5, c = idx & 31;
    *reinterpret_cast<float4*>(&Bs[r * 132 + c * 4]) =
        *reinterpret_cast<const float4*>(&src[r * 128 + c * 4]);
  }
}

// [64][64] -> pitch 68
DEVFN void st64x(int tid, const float* __restrict__ src, float* __restrict__ Bs) {
  for (int idx = tid; idx < 1024; idx += 512) {
    const int r = idx >> 4, c = idx & 15;
    *reinterpret_cast<float4*>(&Bs[r * 68 + c * 4]) =
        *reinterpret_cast<const float4*>(&src[r * 64 + c * 4]);
  }
}

// ============ k-split GEMM cores ============
// 512 thr = 4 k-groups (g=tid>>7) x 128 (t=tid&127). Thread tile: 4 rows x 4 cols.
// c0 = 4*(t&31), r0 = 4*(t>>5). Group g covers k in [g*KG, (g+1)*KG) of staged chunk.
// B-read: 32 distinct float4/half-wave (2-way) conflict-free; A-read: broadcast.

template<int KG>
DEVFN void cks(int tid, const float* __restrict__ A, int lda,
               const float* __restrict__ Bs, float (&acc)[4][4]) {
  const int g = tid >> 7, t = tid & 127;
  const int c0 = (t & 31) * 4, r0 = (t >> 5) * 4;
  const int k0 = g * KG;
#pragma unroll
  for (int kk = 0; kk < KG; ++kk) {
    const int k = k0 + kk;
    const float4 bv = *reinterpret_cast<const float4*>(&Bs[k * 132 + c0]);
    float a[4];
#pragma unroll
    for (int i = 0; i < 4; ++i) a[i] = A[(r0 + i) * lda + k];
#pragma unroll
    for (int i = 0; i < 4; ++i) {
      acc[i][0] += a[i] * bv.x; acc[i][1] += a[i] * bv.y;
      acc[i][2] += a[i] * bv.z; acc[i][3] += a[i] * bv.w;
    }
  }
}

template<int KG>
DEVFN void cks2(int tid, const float* __restrict__ A0, const float* __restrict__ A1,
                int lda, const float* __restrict__ Bs,
                float (&aa)[4][4], float (&ap)[4][4]) {
  const int g = tid >> 7, t = tid & 127;
  const int c0 = (t & 31) * 4, r0 = (t >> 5) * 4;
  const int k0 = g * KG;
#pragma unroll
  for (int kk = 0; kk < KG; ++kk) {
    const int k = k0 + kk;
    const float4 bv = *reinterpret_cast<const float4*>(&Bs[k * 132 + c0]);
#pragma unroll
    for (int i = 0; i < 4; ++i) {
      const float x = A0[(r0 + i) * lda + k];
      const float y = A1[(r0 + i) * lda + k];
      aa[i][0] += x * bv.x; aa[i][1] += x * bv.y; aa[i][2] += x * bv.z; aa[i][3] += x * bv.w;
      ap[i][0] += y * bv.x; ap[i][1] += y * bv.y; ap[i][2] += y * bv.z; ap[i][3] += y * bv.w;
    }
  }
}

// 64-col variant: Bs pitch 68, thread tile 4 rows x 2 cols, c0 = 2*(t&31)
template<int KG>
DEVFN void cksH(int tid, const float* __restrict__ A, int lda,
                const float* __restrict__ Bs, float (&acc)[4][2]) {
  const int g = tid >> 7, t = tid & 127;
  const int c0 = (t & 31) * 2, r0 = (t >> 5) * 4;
  const int k0 = g * KG;
#pragma unroll
  for (int kk = 0; kk < KG; ++kk) {
    const int k = k0 + kk;
    const float2 bv = *reinterpret_cast<const float2*>(&Bs[k * 68 + c0]);
#pragma unroll
    for (int i = 0; i < 4; ++i) {
      const float a = A[(r0 + i) * lda + k];
      acc[i][0] += a * bv.x; acc[i][1] += a * bv.y;
    }
  }
}

// partial write (groups 1..3) -> Red [3][16][132]
DEVFN void wpart(int tid, float* __restrict__ Red, const float (&acc)[4][4]) {
  if (tid >= 128) {
    const int g = tid >> 7, t = tid & 127;
    const int c0 = (t & 31) * 4, r0 = (t >> 5) * 4;
    float* dst = Red + (g - 1) * 2112;
#pragma unroll
    for (int i = 0; i < 4; ++i) {
      float4 v; v.x = acc[i][0]; v.y = acc[i][1]; v.z = acc[i][2]; v.w = acc[i][3];
      *reinterpret_cast<float4*>(&dst[(r0 + i) * 132 + c0]) = v;
    }
  }
}

DEVFN void rsum(int tid, const float* __restrict__ Red, float (&acc)[4][4]) {
  const int c0 = (tid & 31) * 4, r0 = (tid >> 5) * 4;
#pragma unroll
  for (int q = 0; q < 3; ++q) {
    const float* src = Red + q * 2112;
#pragma unroll
    for (int i = 0; i < 4; ++i) {
      const float4 v = *reinterpret_cast<const float4*>(&src[(r0 + i) * 132 + c0]);
      acc[i][0] += v.x; acc[i][1] += v.y; acc[i][2] += v.z; acc[i][3] += v.w;
    }
  }
}

DEVFN void wpartH(int tid, float* __restrict__ Red, const float (&acc)[4][2]) {
  if (tid >= 128) {
    const int g = tid >> 7, t = tid & 127;
    const int c0 = (t & 31) * 2, r0 = (t >> 5) * 4;
    float* dst = Red + (g - 1) * 1056;
#pragma unroll
    for (int i = 0; i < 4; ++i) {
      float2 v; v.x = acc[i][0]; v.y = acc[i][1];
      *reinterpret_cast<float2*>(&dst[(r0 + i) * 66 + c0]) = v;
    }
  }
}

DEVFN void rsumH(int tid, const float* __restrict__ Red, float (&acc)[4][2]) {
  const int c0 = (tid & 31) * 2, r0 = (tid >> 5) * 4;
#pragma unroll
  for (int q = 0; q < 3; ++q) {
    const float* src = Red + q * 1056;
#pragma unroll
    for (int i = 0; i < 4; ++i) {
      const float2 v = *reinterpret_cast<const float2*>(&src[(r0 + i) * 66 + c0]);
      acc[i][0] += v.x; acc[i][1] += v.y;
    }
  }
}

// epilogue by t<128 (caller guards): 4 rows x 4 cols -> row-major O
template<bool ACT, bool HASB>
DEVFN void epi(int tid, const float (&acc)[4][4], float* __restrict__ O, int ldo,
               const float* __restrict__ bias) {
  const int c0 = (tid & 31) * 4, r0 = (tid >> 5) * 4;
#pragma unroll
  for (int i = 0; i < 4; ++i) {
    float t[4];
#pragma unroll
    for (int jj = 0; jj < 4; ++jj) {
      float x = acc[i][jj];
      if constexpr (HASB) x += bias[c0 + jj];
      if constexpr (ACT) x = (x > 0.f) ? x : NSLOPE * x;
      t[jj] = x;
    }
    float4 v; v.x = t[0]; v.y = t[1]; v.z = t[2]; v.w = t[3];
    *reinterpret_cast<float4*>(&O[(r0 + i) * ldo + c0]) = v;
  }
}

// ============ score + softmax: 512 thr, 16 rows (2 rows per wave) ============

DEVFN void score_half(int tid, const float* __restrict__ Qs, int hoff,
                      const float* __restrict__ Ks, float (&acc)[2]) {
  const int j = tid & 63, iw = tid >> 6;
#pragma unroll 2
  for (int kt = 0; kt < 64; kt += 8) {
    float qv[2][8];
#pragma unroll
    for (int r = 0; r < 2; ++r) {
      *reinterpret_cast<float4*>(&qv[r][0]) =
          *reinterpret_cast<const float4*>(&Qs[(iw * 2 + r) * 132 + hoff + kt]);
      *reinterpret_cast<float4*>(&qv[r][4]) =
          *reinterpret_cast<const float4*>(&Qs[(iw * 2 + r) * 132 + hoff + kt + 4]);
    }
#pragma unroll
    for (int kk = 0; kk < 8; ++kk) {
      const float kv = Ks[(kt + kk) * 68 + j];
      acc[0] += qv[0][kk] * kv;
      acc[1] += qv[1][kk] * kv;
    }
  }
}

DEVFN void softmax_write(int tid, float (&acc)[2], float* __restrict__ Wp,
                         float* __restrict__ gout) {
  const int j = tid & 63, iw = tid >> 6;
#pragma unroll
  for (int r = 0; r < 2; ++r) {
    float v = acc[r] * SCALE;
    float m = v;
#pragma unroll
    for (int off = 32; off > 0; off >>= 1) m = fmaxf(m, __shfl_xor(m, off, 64));
    const float p = __expf(v - m);
    float s = p;
#pragma unroll
    for (int off = 32; off > 0; off >>= 1) s += __shfl_xor(s, off, 64);
    const float w = p / s;
    Wp[(iw * 2 + r) * 68 + j] = w;
    gout[(iw * 2 + r) * 64 + j] = w;
  }
}

// ===================== kernels =====================

__global__ void transpose_all(const float* __restrict__ Wpre, const float* __restrict__ Wq,
                              const float* __restrict__ Wse, const float* __restrict__ Wsap,
                              const float* __restrict__ Wav, const float* __restrict__ Wf1,
                              float* __restrict__ ws) {
  const int m = blockIdx.y;
  const float* src; int Cout, K, off;
  switch (m) {
    case 0: src = Wpre; Cout = 128; K = 64;  off = OFF_WPRET; break;
    case 1: src = Wq;   Cout = 128; K = 128; off = OFF_WQT;   break;
    case 2: src = Wse;  Cout = 128; K = 128; off = OFF_WSET;  break;
    case 3: src = Wsap; Cout = 128; K = 96;  off = OFF_WSAPT; break;
    case 4: src = Wav;  Cout = 128; K = 128; off = OFF_WAVT;  break;
    default: src = Wf1; Cout = 64;  K = 128; off = OFF_WF1T;  break;
  }
  const int idx = blockIdx.x * 256 + threadIdx.x;
  if (idx < Cout * K) {
    const int c = idx / K, k = idx - c * K;
    ws[off + k * Cout + c] = src[idx];
  }
}

// M = Wq^T @ Wk. Grid 8 x 512, 16 rows, simple R=1 core (tiny kernel).
__global__ __launch_bounds__(512) void make_M(const float* __restrict__ Wkey,
                                              float* __restrict__ ws) {
  __shared__ float As[16 * 132];
  __shared__ float Bs[64 * 132];
  const int tid = threadIdx.x;
  const int r0 = blockIdx.x * 16;
  {
    const int r = tid >> 5, c = tid & 31;
    *reinterpret_cast<float4*>(&As[r * 132 + c * 4]) =
        *reinterpret_cast<const float4*>(&ws[OFF_WQT + (r0 + r) * 128 + c * 4]);
  }
  const int c0 = (tid & 31) * 4, rg = tid >> 5;
  float acc[4] = {};
  for (int h = 0; h < 2; ++h) {
    __syncthreads();
    st128(tid, Wkey + h * 8192, Bs, 64);
    __syncthreads();
#pragma unroll 8
    for (int k = 0; k < 64; ++k) {
      const float4 bv = *reinterpret_cast<const float4*>(&Bs[k * 132 + c0]);
      const float a = As[rg * 132 + h * 64 + k];
      acc[0] += a * bv.x; acc[1] += a * bv.y; acc[2] += a * bv.z; acc[3] += a * bv.w;
    }
  }
  float4 v; v.x = acc[0]; v.y = acc[1]; v.z = acc[2]; v.w = acc[3];
  *reinterpret_cast<float4*>(&ws[OFF_M + (r0 + rg) * 128 + c0]) = v;
}

// P1: grid 256 (b*4+rq), 512 thr, 16 rows.
__global__ __launch_bounds__(512) void P1(const float* __restrict__ states,
                                          const float* __restrict__ policies,
                                          const float* __restrict__ actions,
                                          const float* __restrict__ b_sap,
                                          const float* __restrict__ b_se_pre,
                                          float* __restrict__ ws) {
  __shared__ float Xa[16 * 100], Xp[16 * 100];
  __shared__ float Ea[16 * 132], Ep[16 * 132], Dd[16 * 132], Er[16 * 132];
  __shared__ float Bs[64 * 132];
  __shared__ float Red[3 * 16 * 132];
  const int tid = threadIdx.x;
  const int b = blockIdx.x >> 2, rq = blockIdx.x & 3;
  const int r0g = b * 64 + rq * 16;

  // X load + first B chunk stage
  st128(tid, ws + OFF_WSAPT, Bs, 64);
  for (int idx = tid; idx < 1024; idx += 512) {
    const int r = idx >> 6, c = idx & 63;
    const float s = states[(r0g + r) * 64 + c];
    Xa[r * 100 + c] = s;
    Xp[r * 100 + c] = s;
  }
  {
    const int r = tid >> 5, c = tid & 31;
    Xa[r * 100 + 64 + c] = actions[(r0g + r) * 32 + c];
    Xp[r * 100 + 64 + c] = policies[(r0g + r) * 32 + c];
  }
  __syncthreads();

  // ---- Esap (dual, K=96: 64 + 32) ----
  float aa[4][4] = {}, ap[4][4] = {};
  cks2<16>(tid, Xa, Xp, 100, Bs, aa, ap);
  __syncthreads();
  st128(tid, ws + OFF_WSAPT + 8192, Bs, 32);
  __syncthreads();
  cks2<8>(tid, Xa + 64, Xp + 64, 100, Bs, aa, ap);
  wpart(tid, Red, aa);
  __syncthreads();
  if (tid < 128) { rsum(tid, Red, aa); epi<true, true>(tid, aa, Ea, 132, b_sap); }
  __syncthreads();
  wpart(tid, Red, ap);
  __syncthreads();
  if (tid < 128) { rsum(tid, Red, ap); epi<true, true>(tid, ap, Ep, 132, b_sap); }
  __syncthreads();
  // Ediff + stage Wav chunk1
  for (int idx = tid; idx < 2048; idx += 512) {
    const int r = idx >> 7, c = idx & 127;
    Ep[r * 132 + c] -= Ea[r * 132 + c];
  }
  st128(tid, ws + OFF_WAVT, Bs, 64);
  __syncthreads();

  // ---- av_act / delta (dual, K=128) ----
  float av[4][4] = {}, dl[4][4] = {};
  cks2<16>(tid, Ea, Ep, 132, Bs, av, dl);
  __syncthreads();
  st128(tid, ws + OFF_WAVT + 8192, Bs, 64);
  __syncthreads();
  cks2<16>(tid, Ea + 64, Ep + 64, 132, Bs, av, dl);
  wpart(tid, Red, av);
  __syncthreads();
  if (tid < 128) { rsum(tid, Red, av); epi<false, false>(tid, av, ws + OFF_AVACT + r0g * 128, 128, nullptr); }
  __syncthreads();
  wpart(tid, Red, dl);
  st64x(tid, ws + OFF_WF1T, Bs);  // Bs free (Wav read done)
  __syncthreads();
  if (tid < 128) { rsum(tid, Red, dl); epi<false, false>(tid, dl, Dd, 132, nullptr); }
  __syncthreads();

  // ---- hd = delta @ Wf1^T (K=128, 64 cols) ----
  float ah[4][2] = {};
  cksH<16>(tid, Dd, 132, Bs, ah);
  __syncthreads();
  st64x(tid, ws + OFF_WF1T + 4096, Bs);
  __syncthreads();
  cksH<16>(tid, Dd + 64, 132, Bs, ah);
  wpartH(tid, Red, ah);
  __syncthreads();
  st128(tid, ws + OFF_WPRET, Bs, 64);  // Bs free
  if (tid < 128) {
    rsumH(tid, Red, ah);
    const int c0 = (tid & 31) * 2, r0 = (tid >> 5) * 4;
#pragma unroll
    for (int i = 0; i < 4; ++i) {
      float2 v; v.x = ah[i][0]; v.y = ah[i][1];
      *reinterpret_cast<float2*>(&ws[OFF_HD + (r0g + r0 + i) * 64 + c0]) = v;
    }
  }
  __syncthreads();

  // ---- e = lrelu(states @ Wpre^T + b) (K=64) -> Er + ws.E + ws.ET ----
  float ae[4][4] = {};
  cks<16>(tid, Xa, 100, Bs, ae);
  wpart(tid, Red, ae);
  __syncthreads();
  st128(tid, ws + OFF_M, Bs, 64);  // Bs free
  if (tid < 128) {
    rsum(tid, Red, ae);
    const int c0 = (tid & 31) * 4, r0 = (tid >> 5) * 4;
    float* et = ws + OFF_ET + b * 8192;
#pragma unroll
    for (int i = 0; i < 4; ++i) {
      float t[4];
#pragma unroll
      for (int jj = 0; jj < 4; ++jj) {
        float x = ae[i][jj] + b_se_pre[c0 + jj];
        t[jj] = (x > 0.f) ? x : NSLOPE * x;
      }
      float4 v; v.x = t[0]; v.y = t[1]; v.z = t[2]; v.w = t[3];
      *reinterpret_cast<float4*>(&Er[(r0 + i) * 132 + c0]) = v;
      *reinterpret_cast<float4*>(&ws[OFF_E + (r0g + r0 + i) * 128 + c0]) = v;
#pragma unroll
      for (int jj = 0; jj < 4; ++jj) et[(c0 + jj) * 64 + rq * 16 + r0 + i] = t[jj];
    }
  }
  __syncthreads();

  // ---- f = e @ M (K=128) -> ws.Q ----
  float af[4][4] = {};
  cks<16>(tid, Er, 132, Bs, af);
  __syncthreads();
  st128(tid, ws + OFF_M + 8192, Bs, 64);
  __syncthreads();
  cks<16>(tid, Er + 64, 132, Bs, af);
  wpart(tid, Red, af);
  __syncthreads();
  if (tid < 128) { rsum(tid, Red, af); epi<false, false>(tid, af, ws + OFF_Q + r0g * 128, 128, nullptr); }
}

// P3: grid 256, 512 thr, 16 rows. score1 -> w_pre ; av_pre ; se ; f2.
__global__ __launch_bounds__(512) void P3(const float* __restrict__ b_se,
                                          float* __restrict__ ws,
                                          float* __restrict__ out) {
  __shared__ float Qs[16 * 132];
  __shared__ float Bs[64 * 132];
  __shared__ float Red[3 * 16 * 132];
  __shared__ float Wp[16 * 68], AV[16 * 132], SEr[16 * 132];
  const int tid = threadIdx.x;
  const int b = blockIdx.x >> 2, rq = blockIdx.x & 3;
  const int r0g = b * 64 + rq * 16;

  {
    const int r = tid >> 5, c = tid & 31;
    *reinterpret_cast<float4*>(&Qs[r * 132 + c * 4]) =
        *reinterpret_cast<const float4*>(&ws[OFF_Q + (r0g + r) * 128 + c * 4]);
  }
  st64x(tid, ws + OFF_ET + b * 8192, Bs);
  __syncthreads();
  float sc[2] = {};
  score_half(tid, Qs, 0, Bs, sc);
  __syncthreads();
  st64x(tid, ws + OFF_ET + b * 8192 + 4096, Bs);
  __syncthreads();
  score_half(tid, Qs, 64, Bs, sc);
  softmax_write(tid, sc, Wp, out + BNN + b * 4096 + rq * 1024);
  __syncthreads();

  // av_pre = w_pre @ e[b] (K=64)
  st128(tid, ws + OFF_E + b * 8192, Bs, 64);
  __syncthreads();
  float av[4][4] = {};
  cks<16>(tid, Wp, 68, Bs, av);
  wpart(tid, Red, av);
  __syncthreads();
  st128(tid, ws + OFF_WSET, Bs, 64);
  if (tid < 128) { rsum(tid, Red, av); epi<false, false>(tid, av, AV, 132, nullptr); }
  __syncthreads();

  // se = lrelu(av_pre @ Wse^T + b_se) (K=128) -> SEr + ws.SET
  float as[4][4] = {};
  cks<16>(tid, AV, 132, Bs, as);
  __syncthreads();
  st128(tid, ws + OFF_WSET + 8192, Bs, 64);
  __syncthreads();
  cks<16>(tid, AV + 64, 132, Bs, as);
  wpart(tid, Red, as);
  __syncthreads();
  st128(tid, ws + OFF_M, Bs, 64);
  if (tid < 128) {
    rsum(tid, Red, as);
    const int c0 = (tid & 31) * 4, r0 = (tid >> 5) * 4;
    float* set = ws + OFF_SET + b * 8192;
#pragma unroll
    for (int i = 0; i < 4; ++i) {
      float t[4];
#pragma unroll
      for (int jj = 0; jj < 4; ++jj) {
        float x = as[i][jj] + b_se[c0 + jj];
        t[jj] = (x > 0.f) ? x : NSLOPE * x;
      }
      float4 v; v.x = t[0]; v.y = t[1]; v.z = t[2]; v.w = t[3];
      *reinterpret_cast<float4*>(&SEr[(r0 + i) * 132 + c0]) = v;
#pragma unroll
      for (int jj = 0; jj < 4; ++jj) set[(c0 + jj) * 64 + rq * 16 + r0 + i] = t[jj];
    }
  }
  __syncthreads();

  // f2 = se @ M (K=128) -> ws.Q
  float af[4][4] = {};
  cks<16>(tid, SEr, 132, Bs, af);
  __syncthreads();
  st128(tid, ws + OFF_M + 8192, Bs, 64);
  __syncthreads();
  cks<16>(tid, SEr + 64, 132, Bs, af);
  wpart(tid, Red, af);
  __syncthreads();
  if (tid < 128) { rsum(tid, Red, af); epi<false, false>(tid, af, ws + OFF_Q + r0g * 128, 128, nullptr); }
}

// P4: grid 256, 512 thr, 16 rows. score2 -> w ; node ; h_base ; head.
__global__ __launch_bounds__(512) void P4(const float* __restrict__ Wf2g,
                                          float* __restrict__ ws,
                                          float* __restrict__ out) {
  __shared__ float Qs[16 * 132];
  __shared__ float Bs[64 * 132];
  __shared__ float Red[3 * 16 * 132];
  __shared__ float Wp[16 * 68], NB[16 * 132], Hb[16 * 66];
  __shared__ float Hd[64 * 69];
  __shared__ float Wf2s[64];
  const int tid = threadIdx.x;
  const int b = blockIdx.x >> 2, rq = blockIdx.x & 3;
  const int r0g = b * 64 + rq * 16;

  for (int idx = tid; idx < 4096; idx += 512)
    Hd[(idx >> 6) * 69 + (idx & 63)] = ws[OFF_HD + b * 4096 + idx];
  if (tid < 64) Wf2s[tid] = Wf2g[tid];
  {
    const int r = tid >> 5, c = tid & 31;
    *reinterpret_cast<float4*>(&Qs[r * 132 + c * 4]) =
        *reinterpret_cast<const float4*>(&ws[OFF_Q + (r0g + r) * 128 + c * 4]);
  }
  st64x(tid, ws + OFF_SET + b * 8192, Bs);
  __syncthreads();
  float sc[2] = {};
  score_half(tid, Qs, 0, Bs, sc);
  __syncthreads();
  st64x(tid, ws + OFF_SET + b * 8192 + 4096, Bs);
  __syncthreads();
  score_half(tid, Qs, 64, Bs, sc);
  softmax_write(tid, sc, Wp, out + 2 * BNN + b * 4096 + rq * 1024);
  __syncthreads();

  // node = w @ av_act[b] (K=64)
  st128(tid, ws + OFF_AVACT + b * 8192, Bs, 64);
  __syncthreads();
  float an[4][4] = {};
  cks<16>(tid, Wp, 68, Bs, an);
  wpart(tid, Red, an);
  __syncthreads();
  st64x(tid, ws + OFF_WF1T, Bs);
  if (tid < 128) { rsum(tid, Red, an); epi<false, false>(tid, an, NB, 132, nullptr); }
  __syncthreads();

  // h_base = node @ Wf1^T (K=128, no activation) -> Hb
  float ah[4][2] = {};
  cksH<16>(tid, NB, 132, Bs, ah);
  __syncthreads();
  st64x(tid, ws + OFF_WF1T + 4096, Bs);
  __syncthreads();
  cksH<16>(tid, NB + 64, 132, Bs, ah);
  wpartH(tid, Red, ah);
  __syncthreads();
  if (tid < 128) {
    rsumH(tid, Red, ah);
    const int c0 = (tid & 31) * 2, r0 = (tid >> 5) * 4;
#pragma unroll
    for (int i = 0; i < 4; ++i) {
      float2 v; v.x = ah[i][0]; v.y = ah[i][1];
      *reinterpret_cast<float2*>(&Hb[(r0 + i) * 66 + c0]) = v;
    }
  }
  __syncthreads();

  // head: value[i][j] = sum_f lrelu(Hb[i,f] + w[i,j]*Hd[j,f]) * Wf2[f]
  const int j = tid & 63, iw = tid >> 6;
  float wv[2], a2[2] = {0.f, 0.f};
#pragma unroll
  for (int r = 0; r < 2; ++r) wv[r] = Wp[(iw * 2 + r) * 68 + j];
  for (int f = 0; f < 64; ++f) {
    const float hdv = Hd[j * 69 + f];
    const float wf = Wf2s[f];
#pragma unroll
    for (int r = 0; r < 2; ++r) {
      float t = Hb[(iw * 2 + r) * 66 + f] + wv[r] * hdv;
      t = (t > 0.f) ? t : NSLOPE * t;
      a2[r] += t * wf;
    }
  }
#pragma unroll
  for (int r = 0; r < 2; ++r)
    out[(r0g + iw * 2 + r) * 64 + j] = a2[r];
}

extern "C" void kernel_launch(void* const* d_in, const int* in_sizes, int n_in,
                              void* d_out, int out_size, void* d_ws, size_t ws_size,
                              hipStream_t stream) {
  const float* states   = (const float*)d_in[0];
  const float* policies = (const float*)d_in[1];
  const float* actions  = (const float*)d_in[2];
  const float* W_se_pre = (const float*)d_in[3];
  const float* b_se_pre = (const float*)d_in[4];
  const float* W_key    = (const float*)d_in[5];
  const float* W_query  = (const float*)d_in[6];
  const float* W_se     = (const float*)d_in[7];
  const float* b_se     = (const float*)d_in[8];
  const float* W_sap    = (const float*)d_in[9];
  const float* b_sap    = (const float*)d_in[10];
  const float* W_av     = (const float*)d_in[11];
  const float* W_f1     = (const float*)d_in[12];
  const float* W_f2     = (const float*)d_in[13];
  float* out = (float*)d_out;
  float* ws  = (float*)d_ws;

  transpose_all<<<dim3(64, 6), dim3(256), 0, stream>>>(
      W_se_pre, W_query, W_se, W_sap, W_av, W_f1, ws);
  make_M<<<dim3(8), dim3(512), 0, stream>>>(W_key, ws);
  P1<<<dim3(256), dim3(512), 0, stream>>>(states, policies, actions, b_sap, b_se_pre, ws);
  P3<<<dim3(256), dim3(512), 0, stream>>>(b_se, ws, out);
  P4<<<dim3(256), dim3(512), 0, stream>>>(W_f2, ws, out);
}

// Round 9
// 68.450 us; speedup vs baseline: 1.3554x; 1.3554x over previous
//
#include <hip/hip_runtime.h>

#define DEVFN __device__ __forceinline__

constexpr int BNN = 64 * 64 * 64;              // 262144 per output tensor
constexpr float SCALE = 0.08838834764831845f;  // 1/sqrt(128)
constexpr float NSLOPE = 0.01f;

// ---- ws layout (floats) ---- (11.93 MB, proven)
constexpr int OFF_WPRET = 0;       // [64][128]
constexpr int OFF_WQT   = 8192;    // [128][128] (make_M input)
constexpr int OFF_M     = 24576;   // [128][128]  M = Wq^T Wk
constexpr int OFF_WSET  = 40960;   // [128][128]
constexpr int OFF_WSAPT = 57344;   // [96][128]
constexpr int OFF_WAVT  = 69632;   // [128][128]
constexpr int OFF_WF1T  = 86016;   // [128][64]
constexpr int OFF_E     = 98304;    // [4096][128] e row-major
constexpr int OFF_Q     = 622592;   // [4096][128] f then f2 (same-row aliasing, safe)
constexpr int OFF_ET    = 1146880;  // [B][128][64] e feature-major
constexpr int OFF_SET   = 1671168;  // [B][128][64] se feature-major
constexpr int OFF_AVACT = 2195456;  // [B][64][128]
constexpr int OFF_HD    = 2719744;  // [B][64][64]

// ============ staging: global (tight) -> LDS (padded pitch), 512 threads ============

DEVFN void st128(int tid, const float* __restrict__ src, float* __restrict__ Bs, int rows) {
  const int n4 = rows * 32;
  for (int idx = tid; idx < n4; idx += 512) {
    const int r = idx >> 5, c = idx & 31;
    *reinterpret_cast<float4*>(&Bs[r * 132 + c * 4]) =
        *reinterpret_cast<const float4*>(&src[r * 128 + c * 4]);
  }
}

// [64][64] -> pitch 68
DEVFN void st64x(int tid, const float* __restrict__ src, float* __restrict__ Bs) {
  for (int idx = tid; idx < 1024; idx += 512) {
    const int r = idx >> 4, c = idx & 15;
    *reinterpret_cast<float4*>(&Bs[r * 68 + c * 4]) =
        *reinterpret_cast<const float4*>(&src[r * 64 + c * 4]);
  }
}

// Coalesced feature-major writeout: src LDS [16 rows][132], dst global [128][64]
// at column offset rq*16. Each 4 lanes write one full 64B line.
DEVFN void wrT(int tid, const float* __restrict__ S, float* __restrict__ dst, int rq) {
  const int fr = tid >> 2, a4 = tid & 3;  // 512 thr = 128 features x 4 col-quads
  float t[4];
#pragma unroll
  for (int i = 0; i < 4; ++i) t[i] = S[(a4 * 4 + i) * 132 + fr];
  float4 v; v.x = t[0]; v.y = t[1]; v.z = t[2]; v.w = t[3];
  *reinterpret_cast<float4*>(&dst[fr * 64 + rq * 16 + a4 * 4]) = v;
}

// ============ LDS-fed GEMM cores: 512 thr, 16 rows x 128 cols, 1 row x 4 cols/thread ===

DEVFN void g1(int tid, const float* __restrict__ A, int lda,
              const float* __restrict__ Bs, int K, float (&acc)[4]) {
  const int c0 = (tid & 31) * 4, rg = tid >> 5;
#pragma unroll 8
  for (int k = 0; k < K; ++k) {
    const float4 bv = *reinterpret_cast<const float4*>(&Bs[k * 132 + c0]);
    const float a = A[rg * lda + k];
    acc[0] += a * bv.x; acc[1] += a * bv.y; acc[2] += a * bv.z; acc[3] += a * bv.w;
  }
}

DEVFN void g2A(int tid, const float* __restrict__ A0, const float* __restrict__ A1,
               int lda, const float* __restrict__ Bs, int K,
               float (&a0)[4], float (&a1)[4]) {
  const int c0 = (tid & 31) * 4, rg = tid >> 5;
#pragma unroll 4
  for (int k = 0; k < K; ++k) {
    const float4 bv = *reinterpret_cast<const float4*>(&Bs[k * 132 + c0]);
    const float x = A0[rg * lda + k];
    const float y = A1[rg * lda + k];
    a0[0] += x * bv.x; a0[1] += x * bv.y; a0[2] += x * bv.z; a0[3] += x * bv.w;
    a1[0] += y * bv.x; a1[1] += y * bv.y; a1[2] += y * bv.z; a1[3] += y * bv.w;
  }
}

// 16 rows x 64 cols: c0=2*(tid&31), rg=tid>>5. B pitch 68 float2.
DEVFN void gH(int tid, const float* __restrict__ A, int lda,
              const float* __restrict__ Bs, int K, float (&acc)[2]) {
  const int c0 = (tid & 31) * 2, rg = tid >> 5;
#pragma unroll 8
  for (int k = 0; k < K; ++k) {
    const float2 bv = *reinterpret_cast<const float2*>(&Bs[k * 68 + c0]);
    const float a = A[rg * lda + k];
    acc[0] += a * bv.x; acc[1] += a * bv.y;
  }
}

template<bool ACT, bool HASB>
DEVFN void epi(int tid, const float (&acc)[4], float* __restrict__ O, int ldo,
               const float* __restrict__ bias) {
  const int c0 = (tid & 31) * 4, rg = tid >> 5;
  float t[4];
#pragma unroll
  for (int i = 0; i < 4; ++i) {
    float x = acc[i];
    if constexpr (HASB) x += bias[c0 + i];
    if constexpr (ACT) x = (x > 0.f) ? x : NSLOPE * x;
    t[i] = x;
  }
  float4 v; v.x = t[0]; v.y = t[1]; v.z = t[2]; v.w = t[3];
  *reinterpret_cast<float4*>(&O[rg * ldo + c0]) = v;
}

// ============ score + softmax: 512 thr, 16 rows (2 rows per wave) ============

DEVFN void score_half(int tid, const float* __restrict__ Qs, int hoff,
                      const float* __restrict__ Ks, float (&acc)[2]) {
  const int j = tid & 63, iw = tid >> 6;
#pragma unroll 2
  for (int kt = 0; kt < 64; kt += 8) {
    float qv[2][8];
#pragma unroll
    for (int r = 0; r < 2; ++r) {
      *reinterpret_cast<float4*>(&qv[r][0]) =
          *reinterpret_cast<const float4*>(&Qs[(iw * 2 + r) * 132 + hoff + kt]);
      *reinterpret_cast<float4*>(&qv[r][4]) =
          *reinterpret_cast<const float4*>(&Qs[(iw * 2 + r) * 132 + hoff + kt + 4]);
    }
#pragma unroll
    for (int kk = 0; kk < 8; ++kk) {
      const float kv = Ks[(kt + kk) * 68 + j];
      acc[0] += qv[0][kk] * kv;
      acc[1] += qv[1][kk] * kv;
    }
  }
}

DEVFN void softmax_write(int tid, float (&acc)[2], float* __restrict__ Wp,
                         float* __restrict__ gout) {
  const int j = tid & 63, iw = tid >> 6;
#pragma unroll
  for (int r = 0; r < 2; ++r) {
    float v = acc[r] * SCALE;
    float m = v;
#pragma unroll
    for (int off = 32; off > 0; off >>= 1) m = fmaxf(m, __shfl_xor(m, off, 64));
    const float p = __expf(v - m);
    float s = p;
#pragma unroll
    for (int off = 32; off > 0; off >>= 1) s += __shfl_xor(s, off, 64);
    const float w = p / s;
    Wp[(iw * 2 + r) * 68 + j] = w;
    gout[(iw * 2 + r) * 64 + j] = w;
  }
}

// ===================== kernels =====================

__global__ void transpose_all(const float* __restrict__ Wpre, const float* __restrict__ Wq,
                              const float* __restrict__ Wse, const float* __restrict__ Wsap,
                              const float* __restrict__ Wav, const float* __restrict__ Wf1,
                              float* __restrict__ ws) {
  const int m = blockIdx.y;
  const float* src; int Cout, K, off;
  switch (m) {
    case 0: src = Wpre; Cout = 128; K = 64;  off = OFF_WPRET; break;
    case 1: src = Wq;   Cout = 128; K = 128; off = OFF_WQT;   break;
    case 2: src = Wse;  Cout = 128; K = 128; off = OFF_WSET;  break;
    case 3: src = Wsap; Cout = 128; K = 96;  off = OFF_WSAPT; break;
    case 4: src = Wav;  Cout = 128; K = 128; off = OFF_WAVT;  break;
    default: src = Wf1; Cout = 64;  K = 128; off = OFF_WF1T;  break;
  }
  const int idx = blockIdx.x * 256 + threadIdx.x;
  if (idx < Cout * K) {
    const int c = idx / K, k = idx - c * K;
    ws[off + k * Cout + c] = src[idx];
  }
}

// M = Wq^T @ Wk. Grid 8 x 512, 16 rows.
__global__ __launch_bounds__(512) void make_M(const float* __restrict__ Wkey,
                                              float* __restrict__ ws) {
  __shared__ float As[16 * 132];
  __shared__ float Bs[64 * 132];
  const int tid = threadIdx.x;
  const int r0 = blockIdx.x * 16;
  {
    const int r = tid >> 5, c = tid & 31;
    *reinterpret_cast<float4*>(&As[r * 132 + c * 4]) =
        *reinterpret_cast<const float4*>(&ws[OFF_WQT + (r0 + r) * 128 + c * 4]);
  }
  const int c0 = (tid & 31) * 4, rg = tid >> 5;
  float acc[4] = {};
  for (int h = 0; h < 2; ++h) {
    __syncthreads();
    st128(tid, Wkey + h * 8192, Bs, 64);
    __syncthreads();
#pragma unroll 8
    for (int k = 0; k < 64; ++k) {
      const float4 bv = *reinterpret_cast<const float4*>(&Bs[k * 132 + c0]);
      const float a = As[rg * 132 + h * 64 + k];
      acc[0] += a * bv.x; acc[1] += a * bv.y; acc[2] += a * bv.z; acc[3] += a * bv.w;
    }
  }
  float4 v; v.x = acc[0]; v.y = acc[1]; v.z = acc[2]; v.w = acc[3];
  *reinterpret_cast<float4*>(&ws[OFF_M + (r0 + rg) * 128 + c0]) = v;
}

// P1: grid 256 (XCD-swizzled: wid = (bid&7)*32 + bid>>3), 512 thr, 16 rows.
__global__ __launch_bounds__(512) void P1(const float* __restrict__ states,
                                          const float* __restrict__ policies,
                                          const float* __restrict__ actions,
                                          const float* __restrict__ b_sap,
                                          const float* __restrict__ b_se_pre,
                                          float* __restrict__ ws) {
  __shared__ float Xa[16 * 100], Xp[16 * 100];
  __shared__ float Ea[16 * 132], Ep[16 * 132], Dd[16 * 132], Er[16 * 132];
  __shared__ float Bs[64 * 132];
  const int tid = threadIdx.x;
  const int wid = ((blockIdx.x & 7) << 5) | (blockIdx.x >> 3);
  const int b = wid >> 2, rq = wid & 3;
  const int r0g = b * 64 + rq * 16;

  for (int idx = tid; idx < 1024; idx += 512) {
    const int r = idx >> 6, c = idx & 63;
    const float s = states[(r0g + r) * 64 + c];
    Xa[r * 100 + c] = s;
    Xp[r * 100 + c] = s;
  }
  {
    const int r = tid >> 5, c = tid & 31;
    Xa[r * 100 + 64 + c] = actions[(r0g + r) * 32 + c];
    Xp[r * 100 + 64 + c] = policies[(r0g + r) * 32 + c];
  }
  st128(tid, ws + OFF_WSAPT, Bs, 64);
  __syncthreads();
  float aa[4] = {}, ap[4] = {};
  g2A(tid, Xa, Xp, 100, Bs, 64, aa, ap);
  __syncthreads();
  st128(tid, ws + OFF_WSAPT + 8192, Bs, 32);
  __syncthreads();
  g2A(tid, Xa + 64, Xp + 64, 100, Bs, 32, aa, ap);
  epi<true, true>(tid, aa, Ea, 132, b_sap);
  epi<true, true>(tid, ap, Ep, 132, b_sap);
  __syncthreads();
  for (int idx = tid; idx < 2048; idx += 512) {
    const int r = idx >> 7, c = idx & 127;
    Ep[r * 132 + c] -= Ea[r * 132 + c];
  }
  __syncthreads();
  // av_act / delta (K=128 in 2 chunks)
  st128(tid, ws + OFF_WAVT, Bs, 64);
  __syncthreads();
  float av[4] = {}, dl[4] = {};
  g2A(tid, Ea, Ep, 132, Bs, 64, av, dl);
  __syncthreads();
  st128(tid, ws + OFF_WAVT + 8192, Bs, 64);
  __syncthreads();
  g2A(tid, Ea + 64, Ep + 64, 132, Bs, 64, av, dl);
  epi<false, false>(tid, av, ws + OFF_AVACT + r0g * 128, 128, nullptr);
  epi<false, false>(tid, dl, Dd, 132, nullptr);
  __syncthreads();
  // hd = delta @ Wf1^T (K=128, 2 chunks, 64 cols)
  st64x(tid, ws + OFF_WF1T, Bs);
  __syncthreads();
  float ah[2] = {};
  gH(tid, Dd, 132, Bs, 64, ah);
  __syncthreads();
  st64x(tid, ws + OFF_WF1T + 4096, Bs);
  __syncthreads();
  gH(tid, Dd + 64, 132, Bs, 64, ah);
  {
    const int c0 = (tid & 31) * 2, rg = tid >> 5;
    float2 v; v.x = ah[0]; v.y = ah[1];
    *reinterpret_cast<float2*>(&ws[OFF_HD + (r0g + rg) * 64 + c0]) = v;
  }
  __syncthreads();
  // e = lrelu(states @ Wpre^T + b) -> Er + ws.E (row-major)
  st128(tid, ws + OFF_WPRET, Bs, 64);
  __syncthreads();
  {
    float ae[4] = {};
    g1(tid, Xa, 100, Bs, 64, ae);
    const int c0 = (tid & 31) * 4, rg = tid >> 5;
    float t[4];
#pragma unroll
    for (int i = 0; i < 4; ++i) {
      float x = ae[i] + b_se_pre[c0 + i];
      t[i] = (x > 0.f) ? x : NSLOPE * x;
    }
    float4 v; v.x = t[0]; v.y = t[1]; v.z = t[2]; v.w = t[3];
    *reinterpret_cast<float4*>(&Er[rg * 132 + c0]) = v;
    *reinterpret_cast<float4*>(&ws[OFF_E + (r0g + rg) * 128 + c0]) = v;
  }
  __syncthreads();
  // ET coalesced transpose-write + stage M chunk1
  wrT(tid, Er, ws + OFF_ET + b * 8192, rq);
  st128(tid, ws + OFF_M, Bs, 64);
  __syncthreads();
  // f = e @ M (K=128, 2 chunks) -> ws.Q
  float af[4] = {};
  g1(tid, Er, 132, Bs, 64, af);
  __syncthreads();
  st128(tid, ws + OFF_M + 8192, Bs, 64);
  __syncthreads();
  g1(tid, Er + 64, 132, Bs, 64, af);
  epi<false, false>(tid, af, ws + OFF_Q + r0g * 128, 128, nullptr);
}

// P3: grid 256 (swizzled), 512 thr, 16 rows. score1 -> w_pre ; av_pre ; se ; f2.
__global__ __launch_bounds__(512) void P3(const float* __restrict__ b_se,
                                          float* __restrict__ ws,
                                          float* __restrict__ out) {
  __shared__ float Qs[16 * 132];
  __shared__ float Bs[64 * 132];
  __shared__ float Wp[16 * 68], AV[16 * 132], SEr[16 * 132];
  const int tid = threadIdx.x;
  const int wid = ((blockIdx.x & 7) << 5) | (blockIdx.x >> 3);
  const int b = wid >> 2, rq = wid & 3;
  const int r0g = b * 64 + rq * 16;

  {
    const int r = tid >> 5, c = tid & 31;
    *reinterpret_cast<float4*>(&Qs[r * 132 + c * 4]) =
        *reinterpret_cast<const float4*>(&ws[OFF_Q + (r0g + r) * 128 + c * 4]);
  }
  st64x(tid, ws + OFF_ET + b * 8192, Bs);
  __syncthreads();
  float sc[2] = {};
  score_half(tid, Qs, 0, Bs, sc);
  __syncthreads();
  st64x(tid, ws + OFF_ET + b * 8192 + 4096, Bs);
  __syncthreads();
  score_half(tid, Qs, 64, Bs, sc);
  softmax_write(tid, sc, Wp, out + BNN + b * 4096 + rq * 1024);
  __syncthreads();
  // av_pre = w_pre @ e[b] (K=64)
  st128(tid, ws + OFF_E + b * 8192, Bs, 64);
  __syncthreads();
  {
    float a[4] = {};
    g1(tid, Wp, 68, Bs, 64, a);
    epi<false, false>(tid, a, AV, 132, nullptr);
  }
  __syncthreads();
  // se = lrelu(av_pre @ Wse^T + b_se) (K=128, 2 chunks) -> SEr
  st128(tid, ws + OFF_WSET, Bs, 64);
  __syncthreads();
  float as[4] = {};
  g1(tid, AV, 132, Bs, 64, as);
  __syncthreads();
  st128(tid, ws + OFF_WSET + 8192, Bs, 64);
  __syncthreads();
  g1(tid, AV + 64, 132, Bs, 64, as);
  {
    const int c0 = (tid & 31) * 4, rg = tid >> 5;
    float t[4];
#pragma unroll
    for (int i = 0; i < 4; ++i) {
      float x = as[i] + b_se[c0 + i];
      t[i] = (x > 0.f) ? x : NSLOPE * x;
    }
    float4 v; v.x = t[0]; v.y = t[1]; v.z = t[2]; v.w = t[3];
    *reinterpret_cast<float4*>(&SEr[rg * 132 + c0]) = v;
  }
  __syncthreads();
  // SET coalesced transpose-write + stage M chunk1
  wrT(tid, SEr, ws + OFF_SET + b * 8192, rq);
  st128(tid, ws + OFF_M, Bs, 64);
  __syncthreads();
  // f2 = se @ M (K=128, 2 chunks) -> ws.Q
  float af[4] = {};
  g1(tid, SEr, 132, Bs, 64, af);
  __syncthreads();
  st128(tid, ws + OFF_M + 8192, Bs, 64);
  __syncthreads();
  g1(tid, SEr + 64, 132, Bs, 64, af);
  epi<false, false>(tid, af, ws + OFF_Q + r0g * 128, 128, nullptr);
}

// P4: grid 256 (swizzled), 512 thr, 16 rows. score2 -> w ; node ; h_base ; head.
__global__ __launch_bounds__(512) void P4(const float* __restrict__ Wf2g,
                                          float* __restrict__ ws,
                                          float* __restrict__ out) {
  __shared__ float Qs[16 * 132];
  __shared__ float Bs[64 * 132];
  __shared__ float Wp[16 * 68], NB[16 * 132], Hb[16 * 66];
  __shared__ float Hd[64 * 69];
  __shared__ float Wf2s[64];
  const int tid = threadIdx.x;
  const int wid = ((blockIdx.x & 7) << 5) | (blockIdx.x >> 3);
  const int b = wid >> 2, rq = wid & 3;
  const int r0g = b * 64 + rq * 16;

  for (int idx = tid; idx < 4096; idx += 512)
    Hd[(idx >> 6) * 69 + (idx & 63)] = ws[OFF_HD + b * 4096 + idx];
  if (tid < 64) Wf2s[tid] = Wf2g[tid];
  {
    const int r = tid >> 5, c = tid & 31;
    *reinterpret_cast<float4*>(&Qs[r * 132 + c * 4]) =
        *reinterpret_cast<const float4*>(&ws[OFF_Q + (r0g + r) * 128 + c * 4]);
  }
  st64x(tid, ws + OFF_SET + b * 8192, Bs);
  __syncthreads();
  float sc[2] = {};
  score_half(tid, Qs, 0, Bs, sc);
  __syncthreads();
  st64x(tid, ws + OFF_SET + b * 8192 + 4096, Bs);
  __syncthreads();
  score_half(tid, Qs, 64, Bs, sc);
  softmax_write(tid, sc, Wp, out + 2 * BNN + b * 4096 + rq * 1024);
  __syncthreads();
  // node = w @ av_act[b] (K=64)
  st128(tid, ws + OFF_AVACT + b * 8192, Bs, 64);
  __syncthreads();
  {
    float a[4] = {};
    g1(tid, Wp, 68, Bs, 64, a);
    epi<false, false>(tid, a, NB, 132, nullptr);
  }
  __syncthreads();
  // h_base = node @ Wf1^T (no activation; K=128, 2 chunks)
  st64x(tid, ws + OFF_WF1T, Bs);
  __syncthreads();
  float ah[2] = {};
  gH(tid, NB, 132, Bs, 64, ah);
  __syncthreads();
  st64x(tid, ws + OFF_WF1T + 4096, Bs);
  __syncthreads();
  gH(tid, NB + 64, 132, Bs, 64, ah);
  {
    const int c0 = (tid & 31) * 2, rg = tid >> 5;
    float2 v; v.x = ah[0]; v.y = ah[1];
    *reinterpret_cast<float2*>(&Hb[rg * 66 + c0]) = v;
  }
  __syncthreads();
  // head: value[i][j] = sum_f lrelu(Hb[i,f] + w[i,j]*Hd[j,f]) * Wf2[f]
  const int j = tid & 63, iw = tid >> 6;
  float wv[2], a2[2] = {0.f, 0.f};
#pragma unroll
  for (int r = 0; r < 2; ++r) wv[r] = Wp[(iw * 2 + r) * 68 + j];
  for (int f = 0; f < 64; ++f) {
    const float hdv = Hd[j * 69 + f];
    const float wf = Wf2s[f];
#pragma unroll
    for (int r = 0; r < 2; ++r) {
      float t = Hb[(iw * 2 + r) * 66 + f] + wv[r] * hdv;
      t = (t > 0.f) ? t : NSLOPE * t;
      a2[r] += t * wf;
    }
  }
#pragma unroll
  for (int r = 0; r < 2; ++r)
    out[(r0g + iw * 2 + r) * 64 + j] = a2[r];
}

extern "C" void kernel_launch(void* const* d_in, const int* in_sizes, int n_in,
                              void* d_out, int out_size, void* d_ws, size_t ws_size,
                              hipStream_t stream) {
  const float* states   = (const float*)d_in[0];
  const float* policies = (const float*)d_in[1];
  const float* actions  = (const float*)d_in[2];
  const float* W_se_pre = (const float*)d_in[3];
  const float* b_se_pre = (const float*)d_in[4];
  const float* W_key    = (const float*)d_in[5];
  const float* W_query  = (const float*)d_in[6];
  const float* W_se     = (const float*)d_in[7];
  const float* b_se     = (const float*)d_in[8];
  const float* W_sap    = (const float*)d_in[9];
  const float* b_sap    = (const float*)d_in[10];
  const float* W_av     = (const float*)d_in[11];
  const float* W_f1     = (const float*)d_in[12];
  const float* W_f2     = (const float*)d_in[13];
  float* out = (float*)d_out;
  float* ws  = (float*)d_ws;

  transpose_all<<<dim3(64, 6), dim3(256), 0, stream>>>(
      W_se_pre, W_query, W_se, W_sap, W_av, W_f1, ws);
  make_M<<<dim3(8), dim3(512), 0, stream>>>(W_key, ws);
  P1<<<dim3(256), dim3(512), 0, stream>>>(states, policies, actions, b_sap, b_se_pre, ws);
  P3<<<dim3(256), dim3(512), 0, stream>>>(b_se, ws, out);
  P4<<<dim3(256), dim3(512), 0, stream>>>(W_f2, ws, out);
}

// Round 10
// 64.586 us; speedup vs baseline: 1.4365x; 1.0598x over previous
//
#include <hip/hip_runtime.h>

#define DEVFN __device__ __forceinline__

constexpr int BNN = 64 * 64 * 64;              // 262144 per output tensor
constexpr float SCALE = 0.08838834764831845f;  // 1/sqrt(128)
constexpr float NSLOPE = 0.01f;

// ---- ws layout (floats) ---- (11.93 MB, proven)
constexpr int OFF_WPRET = 0;       // [64][128]
constexpr int OFF_WQT   = 8192;    // [128][128] (make_M input)
constexpr int OFF_M     = 24576;   // [128][128]  M = Wq^T Wk
constexpr int OFF_WSET  = 40960;   // [128][128]
constexpr int OFF_WSAPT = 57344;   // [96][128]
constexpr int OFF_WAVT  = 69632;   // [128][128]
constexpr int OFF_WF1T  = 86016;   // [128][64]
constexpr int OFF_E     = 98304;    // [4096][128] e row-major
constexpr int OFF_Q     = 622592;   // [4096][128] f then f2 (same-row aliasing, safe)
constexpr int OFF_ET    = 1146880;  // [B][128][64] e feature-major
constexpr int OFF_SET   = 1671168;  // [B][128][64] se feature-major
constexpr int OFF_HA    = 2195456;  // [B][64][64]  ha = av_act @ Wf1^T (replaces AVACT)
constexpr int OFF_HD    = 2719744;  // [B][64][64]

// ============ staging: global (tight) -> LDS (padded pitch), 512 threads ============

DEVFN void st128(int tid, const float* __restrict__ src, float* __restrict__ Bs, int rows) {
  const int n4 = rows * 32;
  for (int idx = tid; idx < n4; idx += 512) {
    const int r = idx >> 5, c = idx & 31;
    *reinterpret_cast<float4*>(&Bs[r * 132 + c * 4]) =
        *reinterpret_cast<const float4*>(&src[r * 128 + c * 4]);
  }
}

// [64][64] -> pitch 68
DEVFN void st64x(int tid, const float* __restrict__ src, float* __restrict__ Bs) {
  for (int idx = tid; idx < 1024; idx += 512) {
    const int r = idx >> 4, c = idx & 15;
    *reinterpret_cast<float4*>(&Bs[r * 68 + c * 4]) =
        *reinterpret_cast<const float4*>(&src[r * 64 + c * 4]);
  }
}

// Coalesced feature-major writeout: src LDS [16 rows][132], dst global [128][64]
// at column offset rq*16. Each 4 lanes write one full 64B line.
DEVFN void wrT(int tid, const float* __restrict__ S, float* __restrict__ dst, int rq) {
  const int fr = tid >> 2, a4 = tid & 3;
  float t[4];
#pragma unroll
  for (int i = 0; i < 4; ++i) t[i] = S[(a4 * 4 + i) * 132 + fr];
  float4 v; v.x = t[0]; v.y = t[1]; v.z = t[2]; v.w = t[3];
  *reinterpret_cast<float4*>(&dst[fr * 64 + rq * 16 + a4 * 4]) = v;
}

// ============ LDS-fed GEMM cores: 512 thr, 16 rows x 128 cols, 1 row x 4 cols/thread ===

DEVFN void g1(int tid, const float* __restrict__ A, int lda,
              const float* __restrict__ Bs, int K, float (&acc)[4]) {
  const int c0 = (tid & 31) * 4, rg = tid >> 5;
#pragma unroll 8
  for (int k = 0; k < K; ++k) {
    const float4 bv = *reinterpret_cast<const float4*>(&Bs[k * 132 + c0]);
    const float a = A[rg * lda + k];
    acc[0] += a * bv.x; acc[1] += a * bv.y; acc[2] += a * bv.z; acc[3] += a * bv.w;
  }
}

DEVFN void g2A(int tid, const float* __restrict__ A0, const float* __restrict__ A1,
               int lda, const float* __restrict__ Bs, int K,
               float (&a0)[4], float (&a1)[4]) {
  const int c0 = (tid & 31) * 4, rg = tid >> 5;
#pragma unroll 4
  for (int k = 0; k < K; ++k) {
    const float4 bv = *reinterpret_cast<const float4*>(&Bs[k * 132 + c0]);
    const float x = A0[rg * lda + k];
    const float y = A1[rg * lda + k];
    a0[0] += x * bv.x; a0[1] += x * bv.y; a0[2] += x * bv.z; a0[3] += x * bv.w;
    a1[0] += y * bv.x; a1[1] += y * bv.y; a1[2] += y * bv.z; a1[3] += y * bv.w;
  }
}

// 16 rows x 64 cols: c0=2*(tid&31), rg=tid>>5. B pitch 68 float2.
DEVFN void gH(int tid, const float* __restrict__ A, int lda,
              const float* __restrict__ Bs, int K, float (&acc)[2]) {
  const int c0 = (tid & 31) * 2, rg = tid >> 5;
#pragma unroll 8
  for (int k = 0; k < K; ++k) {
    const float2 bv = *reinterpret_cast<const float2*>(&Bs[k * 68 + c0]);
    const float a = A[rg * lda + k];
    acc[0] += a * bv.x; acc[1] += a * bv.y;
  }
}

// dual-A 64-col variant (hd and ha share the Wf1^T staging)
DEVFN void gH2(int tid, const float* __restrict__ A0, const float* __restrict__ A1,
               int lda, const float* __restrict__ Bs, int K,
               float (&a0)[2], float (&a1)[2]) {
  const int c0 = (tid & 31) * 2, rg = tid >> 5;
#pragma unroll 4
  for (int k = 0; k < K; ++k) {
    const float2 bv = *reinterpret_cast<const float2*>(&Bs[k * 68 + c0]);
    const float x = A0[rg * lda + k];
    const float y = A1[rg * lda + k];
    a0[0] += x * bv.x; a0[1] += x * bv.y;
    a1[0] += y * bv.x; a1[1] += y * bv.y;
  }
}

template<bool ACT, bool HASB>
DEVFN void epi(int tid, const float (&acc)[4], float* __restrict__ O, int ldo,
               const float* __restrict__ bias) {
  const int c0 = (tid & 31) * 4, rg = tid >> 5;
  float t[4];
#pragma unroll
  for (int i = 0; i < 4; ++i) {
    float x = acc[i];
    if constexpr (HASB) x += bias[c0 + i];
    if constexpr (ACT) x = (x > 0.f) ? x : NSLOPE * x;
    t[i] = x;
  }
  float4 v; v.x = t[0]; v.y = t[1]; v.z = t[2]; v.w = t[3];
  *reinterpret_cast<float4*>(&O[rg * ldo + c0]) = v;
}

// ============ score + softmax: 512 thr, 16 rows (2 rows per wave) ============

DEVFN void score_half(int tid, const float* __restrict__ Qs, int hoff,
                      const float* __restrict__ Ks, float (&acc)[2]) {
  const int j = tid & 63, iw = tid >> 6;
#pragma unroll 2
  for (int kt = 0; kt < 64; kt += 8) {
    float qv[2][8];
#pragma unroll
    for (int r = 0; r < 2; ++r) {
      *reinterpret_cast<float4*>(&qv[r][0]) =
          *reinterpret_cast<const float4*>(&Qs[(iw * 2 + r) * 132 + hoff + kt]);
      *reinterpret_cast<float4*>(&qv[r][4]) =
          *reinterpret_cast<const float4*>(&Qs[(iw * 2 + r) * 132 + hoff + kt + 4]);
    }
#pragma unroll
    for (int kk = 0; kk < 8; ++kk) {
      const float kv = Ks[(kt + kk) * 68 + j];
      acc[0] += qv[0][kk] * kv;
      acc[1] += qv[1][kk] * kv;
    }
  }
}

DEVFN void softmax_write(int tid, float (&acc)[2], float* __restrict__ Wp,
                         float* __restrict__ gout) {
  const int j = tid & 63, iw = tid >> 6;
#pragma unroll
  for (int r = 0; r < 2; ++r) {
    float v = acc[r] * SCALE;
    float m = v;
#pragma unroll
    for (int off = 32; off > 0; off >>= 1) m = fmaxf(m, __shfl_xor(m, off, 64));
    const float p = __expf(v - m);
    float s = p;
#pragma unroll
    for (int off = 32; off > 0; off >>= 1) s += __shfl_xor(s, off, 64);
    const float w = p / s;
    Wp[(iw * 2 + r) * 68 + j] = w;
    gout[(iw * 2 + r) * 64 + j] = w;
  }
}

// ===================== kernels =====================

__global__ void transpose_all(const float* __restrict__ Wpre, const float* __restrict__ Wq,
                              const float* __restrict__ Wse, const float* __restrict__ Wsap,
                              const float* __restrict__ Wav, const float* __restrict__ Wf1,
                              float* __restrict__ ws) {
  const int m = blockIdx.y;
  const float* src; int Cout, K, off;
  switch (m) {
    case 0: src = Wpre; Cout = 128; K = 64;  off = OFF_WPRET; break;
    case 1: src = Wq;   Cout = 128; K = 128; off = OFF_WQT;   break;
    case 2: src = Wse;  Cout = 128; K = 128; off = OFF_WSET;  break;
    case 3: src = Wsap; Cout = 128; K = 96;  off = OFF_WSAPT; break;
    case 4: src = Wav;  Cout = 128; K = 128; off = OFF_WAVT;  break;
    default: src = Wf1; Cout = 64;  K = 128; off = OFF_WF1T;  break;
  }
  const int idx = blockIdx.x * 256 + threadIdx.x;
  if (idx < Cout * K) {
    const int c = idx / K, k = idx - c * K;
    ws[off + k * Cout + c] = src[idx];
  }
}

// M = Wq^T @ Wk. Grid 8 x 512, 16 rows.
__global__ __launch_bounds__(512) void make_M(const float* __restrict__ Wkey,
                                              float* __restrict__ ws) {
  __shared__ float As[16 * 132];
  __shared__ float Bs[64 * 132];
  const int tid = threadIdx.x;
  const int r0 = blockIdx.x * 16;
  {
    const int r = tid >> 5, c = tid & 31;
    *reinterpret_cast<float4*>(&As[r * 132 + c * 4]) =
        *reinterpret_cast<const float4*>(&ws[OFF_WQT + (r0 + r) * 128 + c * 4]);
  }
  const int c0 = (tid & 31) * 4, rg = tid >> 5;
  float acc[4] = {};
  for (int h = 0; h < 2; ++h) {
    __syncthreads();
    st128(tid, Wkey + h * 8192, Bs, 64);
    __syncthreads();
#pragma unroll 8
    for (int k = 0; k < 64; ++k) {
      const float4 bv = *reinterpret_cast<const float4*>(&Bs[k * 132 + c0]);
      const float a = As[rg * 132 + h * 64 + k];
      acc[0] += a * bv.x; acc[1] += a * bv.y; acc[2] += a * bv.z; acc[3] += a * bv.w;
    }
  }
  float4 v; v.x = acc[0]; v.y = acc[1]; v.z = acc[2]; v.w = acc[3];
  *reinterpret_cast<float4*>(&ws[OFF_M + (r0 + rg) * 128 + c0]) = v;
}

// P1: grid 256 (XCD-swizzled), 512 thr, 16 rows. LDS 76.5 KB -> 2 blocks/CU.
__global__ __launch_bounds__(512) void P1(const float* __restrict__ states,
                                          const float* __restrict__ policies,
                                          const float* __restrict__ actions,
                                          const float* __restrict__ b_sap,
                                          const float* __restrict__ b_se_pre,
                                          float* __restrict__ ws) {
  __shared__ float S[16 * 68];             // states rows (K=64 A-operand)
  __shared__ float Aa[16 * 36], Ap[16 * 36]; // action / policy tails
  __shared__ float Ea[16 * 132];           // E_act, then AVs (av_act rows)
  __shared__ float Ep[16 * 132], Dd[16 * 132], Er[16 * 132];
  __shared__ float Bs[64 * 132];
  const int tid = threadIdx.x;
  const int wid = ((blockIdx.x & 7) << 5) | (blockIdx.x >> 3);
  const int b = wid >> 2, rq = wid & 3;
  const int r0g = b * 64 + rq * 16;

  for (int idx = tid; idx < 1024; idx += 512) {
    const int r = idx >> 6, c = idx & 63;
    S[r * 68 + c] = states[(r0g + r) * 64 + c];
  }
  {
    const int r = tid >> 5, c = tid & 31;
    Aa[r * 36 + c] = actions[(r0g + r) * 32 + c];
    Ap[r * 36 + c] = policies[(r0g + r) * 32 + c];
  }
  st128(tid, ws + OFF_WSAPT, Bs, 64);
  __syncthreads();
  // common (state) part of Esap, K=64
  float cm[4] = {};
  g1(tid, S, 68, Bs, 64, cm);
  __syncthreads();
  st128(tid, ws + OFF_WSAPT + 8192, Bs, 32);
  __syncthreads();
  // act/pol tails, K=32
  float aa[4] = {cm[0], cm[1], cm[2], cm[3]};
  float ap[4] = {cm[0], cm[1], cm[2], cm[3]};
  g2A(tid, Aa, Ap, 36, Bs, 32, aa, ap);
  epi<true, true>(tid, aa, Ea, 132, b_sap);
  epi<true, true>(tid, ap, Ep, 132, b_sap);
  __syncthreads();
  for (int idx = tid; idx < 2048; idx += 512) {
    const int r = idx >> 7, c = idx & 127;
    Ep[r * 132 + c] -= Ea[r * 132 + c];
  }
  __syncthreads();
  // av_act / delta (K=128 in 2 chunks)
  st128(tid, ws + OFF_WAVT, Bs, 64);
  __syncthreads();
  float av[4] = {}, dl[4] = {};
  g2A(tid, Ea, Ep, 132, Bs, 64, av, dl);
  __syncthreads();
  st128(tid, ws + OFF_WAVT + 8192, Bs, 64);
  __syncthreads();
  g2A(tid, Ea + 64, Ep + 64, 132, Bs, 64, av, dl);
  __syncthreads();  // all g2A reads of Ea done before overwrite
  epi<false, false>(tid, av, Ea, 132, nullptr);  // Ea := AVs (av_act rows, LDS only)
  epi<false, false>(tid, dl, Dd, 132, nullptr);
  __syncthreads();
  // hd = delta @ Wf1^T and ha = av_act @ Wf1^T (shared staging, K=128 in 2 chunks)
  st64x(tid, ws + OFF_WF1T, Bs);
  __syncthreads();
  float ah[2] = {}, aha[2] = {};
  gH2(tid, Dd, Ea, 132, Bs, 64, ah, aha);
  __syncthreads();
  st64x(tid, ws + OFF_WF1T + 4096, Bs);
  __syncthreads();
  gH2(tid, Dd + 64, Ea + 64, 132, Bs, 64, ah, aha);
  {
    const int c0 = (tid & 31) * 2, rg = tid >> 5;
    float2 vh; vh.x = ah[0]; vh.y = ah[1];
    float2 va; va.x = aha[0]; va.y = aha[1];
    *reinterpret_cast<float2*>(&ws[OFF_HD + (r0g + rg) * 64 + c0]) = vh;
    *reinterpret_cast<float2*>(&ws[OFF_HA + (r0g + rg) * 64 + c0]) = va;
  }
  __syncthreads();
  // e = lrelu(states @ Wpre^T + b) -> Er + ws.E (row-major)
  st128(tid, ws + OFF_WPRET, Bs, 64);
  __syncthreads();
  {
    float ae[4] = {};
    g1(tid, S, 68, Bs, 64, ae);
    const int c0 = (tid & 31) * 4, rg = tid >> 5;
    float t[4];
#pragma unroll
    for (int i = 0; i < 4; ++i) {
      float x = ae[i] + b_se_pre[c0 + i];
      t[i] = (x > 0.f) ? x : NSLOPE * x;
    }
    float4 v; v.x = t[0]; v.y = t[1]; v.z = t[2]; v.w = t[3];
    *reinterpret_cast<float4*>(&Er[rg * 132 + c0]) = v;
    *reinterpret_cast<float4*>(&ws[OFF_E + (r0g + rg) * 128 + c0]) = v;
  }
  __syncthreads();
  // ET coalesced transpose-write + stage M chunk1
  wrT(tid, Er, ws + OFF_ET + b * 8192, rq);
  st128(tid, ws + OFF_M, Bs, 64);
  __syncthreads();
  // f = e @ M (K=128, 2 chunks) -> ws.Q
  float af[4] = {};
  g1(tid, Er, 132, Bs, 64, af);
  __syncthreads();
  st128(tid, ws + OFF_M + 8192, Bs, 64);
  __syncthreads();
  g1(tid, Er + 64, 132, Bs, 64, af);
  epi<false, false>(tid, af, ws + OFF_Q + r0g * 128, 128, nullptr);
}

// P3: grid 256 (swizzled), 512 thr, 16 rows. score1 -> w_pre ; av_pre ; se ; f2.
__global__ __launch_bounds__(512) void P3(const float* __restrict__ b_se,
                                          float* __restrict__ ws,
                                          float* __restrict__ out) {
  __shared__ float Qs[16 * 132];
  __shared__ float Bs[64 * 132];
  __shared__ float Wp[16 * 68], AV[16 * 132], SEr[16 * 132];
  const int tid = threadIdx.x;
  const int wid = ((blockIdx.x & 7) << 5) | (blockIdx.x >> 3);
  const int b = wid >> 2, rq = wid & 3;
  const int r0g = b * 64 + rq * 16;

  {
    const int r = tid >> 5, c = tid & 31;
    *reinterpret_cast<float4*>(&Qs[r * 132 + c * 4]) =
        *reinterpret_cast<const float4*>(&ws[OFF_Q + (r0g + r) * 128 + c * 4]);
  }
  st64x(tid, ws + OFF_ET + b * 8192, Bs);
  __syncthreads();
  float sc[2] = {};
  score_half(tid, Qs, 0, Bs, sc);
  __syncthreads();
  st64x(tid, ws + OFF_ET + b * 8192 + 4096, Bs);
  __syncthreads();
  score_half(tid, Qs, 64, Bs, sc);
  softmax_write(tid, sc, Wp, out + BNN + b * 4096 + rq * 1024);
  __syncthreads();
  // av_pre = w_pre @ e[b] (K=64)
  st128(tid, ws + OFF_E + b * 8192, Bs, 64);
  __syncthreads();
  {
    float a[4] = {};
    g1(tid, Wp, 68, Bs, 64, a);
    epi<false, false>(tid, a, AV, 132, nullptr);
  }
  __syncthreads();
  // se = lrelu(av_pre @ Wse^T + b_se) (K=128, 2 chunks) -> SEr
  st128(tid, ws + OFF_WSET, Bs, 64);
  __syncthreads();
  float as[4] = {};
  g1(tid, AV, 132, Bs, 64, as);
  __syncthreads();
  st128(tid, ws + OFF_WSET + 8192, Bs, 64);
  __syncthreads();
  g1(tid, AV + 64, 132, Bs, 64, as);
  {
    const int c0 = (tid & 31) * 4, rg = tid >> 5;
    float t[4];
#pragma unroll
    for (int i = 0; i < 4; ++i) {
      float x = as[i] + b_se[c0 + i];
      t[i] = (x > 0.f) ? x : NSLOPE * x;
    }
    float4 v; v.x = t[0]; v.y = t[1]; v.z = t[2]; v.w = t[3];
    *reinterpret_cast<float4*>(&SEr[rg * 132 + c0]) = v;
  }
  __syncthreads();
  // SET coalesced transpose-write + stage M chunk1
  wrT(tid, SEr, ws + OFF_SET + b * 8192, rq);
  st128(tid, ws + OFF_M, Bs, 64);
  __syncthreads();
  // f2 = se @ M (K=128, 2 chunks) -> ws.Q
  float af[4] = {};
  g1(tid, SEr, 132, Bs, 64, af);
  __syncthreads();
  st128(tid, ws + OFF_M + 8192, Bs, 64);
  __syncthreads();
  g1(tid, SEr + 64, 132, Bs, 64, af);
  epi<false, false>(tid, af, ws + OFF_Q + r0g * 128, 128, nullptr);
}

// P4: grid 256 (swizzled), 512 thr, 16 rows. score2 -> w ; h_base = w @ ha ; head.
__global__ __launch_bounds__(512) void P4(const float* __restrict__ Wf2g,
                                          float* __restrict__ ws,
                                          float* __restrict__ out) {
  __shared__ float Qs[16 * 132];
  __shared__ float Bs[64 * 132];
  __shared__ float Wp[16 * 68], Hb[16 * 66];
  __shared__ float Hd[64 * 69];
  __shared__ float Wf2s[64];
  const int tid = threadIdx.x;
  const int wid = ((blockIdx.x & 7) << 5) | (blockIdx.x >> 3);
  const int b = wid >> 2, rq = wid & 3;
  const int r0g = b * 64 + rq * 16;

  for (int idx = tid; idx < 4096; idx += 512)
    Hd[(idx >> 6) * 69 + (idx & 63)] = ws[OFF_HD + b * 4096 + idx];
  if (tid < 64) Wf2s[tid] = Wf2g[tid];
  {
    const int r = tid >> 5, c = tid & 31;
    *reinterpret_cast<float4*>(&Qs[r * 132 + c * 4]) =
        *reinterpret_cast<const float4*>(&ws[OFF_Q + (r0g + r) * 128 + c * 4]);
  }
  st64x(tid, ws + OFF_SET + b * 8192, Bs);
  __syncthreads();
  float sc[2] = {};
  score_half(tid, Qs, 0, Bs, sc);
  __syncthreads();
  st64x(tid, ws + OFF_SET + b * 8192 + 4096, Bs);
  __syncthreads();
  score_half(tid, Qs, 64, Bs, sc);
  softmax_write(tid, sc, Wp, out + 2 * BNN + b * 4096 + rq * 1024);
  __syncthreads();
  // h_base = w @ ha[b] (K=64)
  st64x(tid, ws + OFF_HA + b * 4096, Bs);
  __syncthreads();
  float ah[2] = {};
  gH(tid, Wp, 68, Bs, 64, ah);
  {
    const int c0 = (tid & 31) * 2, rg = tid >> 5;
    float2 v; v.x = ah[0]; v.y = ah[1];
    *reinterpret_cast<float2*>(&Hb[rg * 66 + c0]) = v;
  }
  __syncthreads();
  // head: value[i][j] = sum_f lrelu(Hb[i,f] + w[i,j]*Hd[j,f]) * Wf2[f]
  const int j = tid & 63, iw = tid >> 6;
  float wv[2], a2[2] = {0.f, 0.f};
#pragma unroll
  for (int r = 0; r < 2; ++r) wv[r] = Wp[(iw * 2 + r) * 68 + j];
  for (int f = 0; f < 64; ++f) {
    const float hdv = Hd[j * 69 + f];
    const float wf = Wf2s[f];
#pragma unroll
    for (int r = 0; r < 2; ++r) {
      float t = Hb[(iw * 2 + r) * 66 + f] + wv[r] * hdv;
      t = (t > 0.f) ? t : NSLOPE * t;
      a2[r] += t * wf;
    }
  }
#pragma unroll
  for (int r = 0; r < 2; ++r)
    out[(r0g + iw * 2 + r) * 64 + j] = a2[r];
}

extern "C" void kernel_launch(void* const* d_in, const int* in_sizes, int n_in,
                              void* d_out, int out_size, void* d_ws, size_t ws_size,
                              hipStream_t stream) {
  const float* states   = (const float*)d_in[0];
  const float* policies = (const float*)d_in[1];
  const float* actions  = (const float*)d_in[2];
  const float* W_se_pre = (const float*)d_in[3];
  const float* b_se_pre = (const float*)d_in[4];
  const float* W_key    = (const float*)d_in[5];
  const float* W_query  = (const float*)d_in[6];
  const float* W_se     = (const float*)d_in[7];
  const float* b_se     = (const float*)d_in[8];
  const float* W_sap    = (const float*)d_in[9];
  const float* b_sap    = (const float*)d_in[10];
  const float* W_av     = (const float*)d_in[11];
  const float* W_f1     = (const float*)d_in[12];
  const float* W_f2     = (const float*)d_in[13];
  float* out = (float*)d_out;
  float* ws  = (float*)d_ws;

  transpose_all<<<dim3(64, 6), dim3(256), 0, stream>>>(
      W_se_pre, W_query, W_se, W_sap, W_av, W_f1, ws);
  make_M<<<dim3(8), dim3(512), 0, stream>>>(W_key, ws);
  P1<<<dim3(256), dim3(512), 0, stream>>>(states, policies, actions, b_sap, b_se_pre, ws);
  P3<<<dim3(256), dim3(512), 0, stream>>>(b_se, ws, out);
  P4<<<dim3(256), dim3(512), 0, stream>>>(W_f2, ws, out);
}